// Round 10
// baseline (348.067 us; speedup 1.0000x reference)
//
#include <hip/hip_runtime.h>
#include <hip/hip_cooperative_groups.h>
#include <math.h>

namespace cg = cooperative_groups;

#define BATCH   256
#define IN_F    2048
#define OUT_F   256
#define NCOL    2048    /* OUT_F*KD */
#define OSTRIDE 2304    /* IN_F + OUT_F */
#define LOG2E   1.4426950408889634f

typedef float    f32x4  __attribute__((ext_vector_type(4)));
typedef short    bf16x8 __attribute__((ext_vector_type(8)));
typedef _Float16 h16x2  __attribute__((ext_vector_type(2)));
typedef __fp16   fp16x2 __attribute__((ext_vector_type(2)));
typedef unsigned short u16;
typedef unsigned int   u32;

// ws layout:
//   [0, 1MB)   Mh f16 [256 o][256 j][8 k]
//   [16,24MB)  Wt bf16 tiled [nt(128)][kc(256)][n16(16)][8]
//   [64,65MB)  Xb bf16 tiled [rt(16)][kc(256)][r16(16)][8] (pre *log2e)
#define WT_BASE   (16u << 20)
#define XB_BASE   (64u << 20)

__device__ __forceinline__ u16 f2bf(float f) {
    unsigned u = __builtin_bit_cast(unsigned, f);
    u += 0x7fff + ((u >> 16) & 1);              // RNE
    return (u16)(u >> 16);
}

__device__ __forceinline__ float exp2_fast(float x) {
#if __has_builtin(__builtin_amdgcn_exp2f)
    return __builtin_amdgcn_exp2f(x);
#else
    float r; asm("v_exp_f32 %0, %1" : "=v"(r) : "v"(x)); return r;
#endif
}

__device__ __forceinline__ float hsum_neg(h16x2 s) {
#if __has_builtin(__builtin_amdgcn_fdot2)
    const h16x2 n1 = {(_Float16)-1.0f, (_Float16)-1.0f};
    return __builtin_amdgcn_fdot2(s, n1, 0.0f, false);
#else
    return -((float)s[0] + (float)s[1]);
#endif
}

// ---------------------------------------------------------------------------
// Fused single-dispatch pipeline: prep | grid.sync | gemm | grid.sync | pair.
// 512 blocks x 512 threads, 2 blocks/CU (LDS 39.9KB/block, VGPR<=128).
// ---------------------------------------------------------------------------
__global__ __launch_bounds__(512, 4)
void k_fused(const float* __restrict__ X, const float* __restrict__ T,
             u16* __restrict__ Wt, u16* __restrict__ Xb,
             u16* __restrict__ Mh, float* __restrict__ out) {
    __shared__ float L[8][32][33];                // 33.8 KB (gemm reduce)
    __shared__ __align__(16) uint4 Msh[BATCH];    // 4 KB   (pair stage)
    __shared__ float Ps[512];                     // 2 KB   (pair reduce)

    const int bid = blockIdx.x, t = threadIdx.x;
    cg::grid_group grid = cg::this_grid();

    // ================= Phase 1: prep (uniform spread) =================
    {
        const int g = bid * 512 + t;              // 0..262143
        // --- tconv: 16 T-elements -> Wt tiled ---
        {
            const int np = g & 1023;              // n-pair 0..1023
            const int kc = (g >> 10) & 7;
            const int kg = g >> 13;               // 0..31
            const int n  = np * 2;
            const int nt = n >> 4, n16 = n & 15;
            const int kb = kg * 64 + kc * 8;
            u16 h0[8], h1[8];
#pragma unroll
            for (int r = 0; r < 8; ++r) {
                float2 v = *(const float2*)(T + (size_t)(kb + r) * NCOL + n);
                h0[r] = f2bf(v.x);
                h1[r] = f2bf(v.y);
            }
            u16* dst = Wt + ((size_t)(nt * 256 + kg * 8 + kc) * 16 + n16) * 8;
            *(float4*)dst       = *(float4*)h0;
            *(float4*)(dst + 8) = *(float4*)h1;
        }
        // --- xconv + copy: 2 X-elements ---
        {
            const int row = g >> 10;              // 0..255
            const int k   = (g & 1023) * 2;
            float2 v = *(const float2*)(X + (size_t)row * IN_F + k);
            u16 hh[2] = {f2bf(v.x * LOG2E), f2bf(v.y * LOG2E)};
            const int kc = k >> 3, k7 = k & 7, rt = row >> 4, r16 = row & 15;
            *(u32*)(Xb + ((size_t)(rt * 256 + kc) * 16 + r16) * 8 + k7) =
                *(u32*)hh;
            *(float2*)(out + (size_t)row * OSTRIDE + k) = v;
        }
    }
    __threadfence();
    grid.sync();

    // ================= Phase 2: GEMM (8-way in-block split-K) =========
    {
        const int l = t & 63, kcw = t >> 6;
        const int R = bid >> 6;            // 0..7
        const int C = bid & 63;            // 0..63 (bid%8=C%8: XCD grouping)

        const int lo = (l >> 4) * 128 + (l & 15) * 8;
        const u16* ap0 = Xb + (size_t)(R * 2) * 32768 + kcw * 4096 + lo;
        const u16* ap1 = ap0 + 32768;
        const u16* bp0 = Wt + (size_t)(C * 2) * 32768 + kcw * 4096 + lo;
        const u16* bp1 = bp0 + 32768;

        f32x4 c00 = {0.f,0.f,0.f,0.f}, c01 = {0.f,0.f,0.f,0.f};
        f32x4 c10 = {0.f,0.f,0.f,0.f}, c11 = {0.f,0.f,0.f,0.f};

#pragma unroll 4
        for (int s = 0; s < 8; ++s) {
            bf16x8 a0 = *(const bf16x8*)(ap0 + s * 512);
            bf16x8 a1 = *(const bf16x8*)(ap1 + s * 512);
            bf16x8 b0 = *(const bf16x8*)(bp0 + s * 512);
            bf16x8 b1 = *(const bf16x8*)(bp1 + s * 512);
            c00 = __builtin_amdgcn_mfma_f32_16x16x32_bf16(a0, b0, c00, 0, 0, 0);
            c01 = __builtin_amdgcn_mfma_f32_16x16x32_bf16(a0, b1, c01, 0, 0, 0);
            c10 = __builtin_amdgcn_mfma_f32_16x16x32_bf16(a1, b0, c10, 0, 0, 0);
            c11 = __builtin_amdgcn_mfma_f32_16x16x32_bf16(a1, b1, c11, 0, 0, 0);
        }

        const int lq = l >> 4, lm = l & 15;
#define PUT(acc, qi, qj) do { \
        _Pragma("unroll") \
        for (int r = 0; r < 4; ++r) \
            L[kcw][(qj) * 16 + lm][(qi) * 16 + lq * 4 + r] = acc[r]; \
    } while (0)
        PUT(c00, 0, 0); PUT(c01, 0, 1); PUT(c10, 1, 0); PUT(c11, 1, 1);
#undef PUT
        __syncthreads();

        if (t < 256) {
            const int o2 = t >> 6;             // 0..3
            const int jl = (t & 63) >> 1;      // 0..31
            const int k0 = (t & 1) * 4;        // 0 or 4
            float v[4];
#pragma unroll
            for (int i = 0; i < 4; ++i) {
                const int c = o2 * 8 + k0 + i;
                float s0 = (L[0][c][jl] + L[1][c][jl]) + (L[2][c][jl] + L[3][c][jl]);
                float s1 = (L[4][c][jl] + L[5][c][jl]) + (L[6][c][jl] + L[7][c][jl]);
                v[i] = s0 + s1;
            }
            fp16x2 p0 = __builtin_amdgcn_cvt_pkrtz(v[0], v[1]);
            fp16x2 p1 = __builtin_amdgcn_cvt_pkrtz(v[2], v[3]);
            uint2 pk = {__builtin_bit_cast(u32, p0), __builtin_bit_cast(u32, p1)};
            *(uint2*)(Mh + ((size_t)(C * 4 + o2) * 256 + R * 32 + jl) * 8 + k0) = pk;
        }
    }
    __threadfence();
    grid.sync();

    // ================= Phase 3: pairwise L1-exp2 ======================
    {
        const int o  = bid >> 1;           // 0..255
        const int jh = bid & 1;            // j-half
        if (t < 256) Msh[t] = ((const uint4*)(Mh + (size_t)o * 2048))[t];
        __syncthreads();

        const int jl = t & 127, q = t >> 7;    // 128 j x 4 i-quarters
        const int j  = jh * 128 + jl;
        uint4 mm = Msh[j];
        const h16x2 m0 = __builtin_bit_cast(h16x2, mm.x);
        const h16x2 m1 = __builtin_bit_cast(h16x2, mm.y);
        const h16x2 m2 = __builtin_bit_cast(h16x2, mm.z);
        const h16x2 m3 = __builtin_bit_cast(h16x2, mm.w);

        float acc = 0.f;
        const int i0 = q * 64;
#pragma unroll 4
        for (int i = i0; i < i0 + 64; ++i) {
            uint4 uu = Msh[i];                    // broadcast ds_read_b128
            h16x2 d0 = __builtin_bit_cast(h16x2, uu.x) - m0;
            h16x2 d1 = __builtin_bit_cast(h16x2, uu.y) - m1;
            h16x2 d2 = __builtin_bit_cast(h16x2, uu.z) - m2;
            h16x2 d3 = __builtin_bit_cast(h16x2, uu.w) - m3;
            h16x2 e0 = __builtin_bit_cast(h16x2, __builtin_bit_cast(u32, d0) & 0x7fff7fffu);
            h16x2 e1 = __builtin_bit_cast(h16x2, __builtin_bit_cast(u32, d1) & 0x7fff7fffu);
            h16x2 e2 = __builtin_bit_cast(h16x2, __builtin_bit_cast(u32, d2) & 0x7fff7fffu);
            h16x2 e3 = __builtin_bit_cast(h16x2, __builtin_bit_cast(u32, d3) & 0x7fff7fffu);
            h16x2 s = (e0 + e1) + (e2 + e3);
            acc += exp2_fast(hsum_neg(s));
        }
        Ps[t] = acc;
        __syncthreads();
        if (t < 128)
            out[(size_t)(jh * 128 + t) * OSTRIDE + IN_F + o] =
                ((Ps[t] + Ps[t + 128]) + (Ps[t + 256] + Ps[t + 384])) - 1.0f;
    }
}

extern "C" void kernel_launch(void* const* d_in, const int* in_sizes, int n_in,
                              void* d_out, int out_size, void* d_ws, size_t ws_size,
                              hipStream_t stream) {
    const float* x = (const float*)d_in[0];   // [256, 2048]
    const float* T = (const float*)d_in[1];   // [2048][2048] flattened
    float* out = (float*)d_out;               // [256, 2304]
    char* ws = (char*)d_ws;
    u16* Mh = (u16*)ws;
    u16* Wt = (u16*)(ws + WT_BASE);
    u16* Xb = (u16*)(ws + XB_BASE);

    void* args[] = {(void*)&x, (void*)&T, (void*)&Wt, (void*)&Xb,
                    (void*)&Mh, (void*)&out};
    hipLaunchCooperativeKernel((void*)k_fused, dim3(512), dim3(512),
                               args, 0, stream);
}

// Round 11
// 234.965 us; speedup vs baseline: 1.4814x; 1.4814x over previous
//
#include <hip/hip_runtime.h>
#include <math.h>

#define BATCH   256
#define IN_F    2048
#define OUT_F   256
#define NCOL    2048    /* OUT_F*KD */
#define OSTRIDE 2304    /* IN_F + OUT_F */
#define LOG2E   1.4426950408889634f

typedef float    f32x4  __attribute__((ext_vector_type(4)));
typedef short    bf16x8 __attribute__((ext_vector_type(8)));
typedef _Float16 h16x2  __attribute__((ext_vector_type(2)));
typedef __fp16   fp16x2 __attribute__((ext_vector_type(2)));
typedef unsigned short u16;
typedef unsigned int   u32;

// ws layout (diagnostic, 3 operand regions with identical contents):
//   [0, 1MB)          Mh f16 [256 o][256 j][8 k]
//   16MB + r*8MB      Wt[r] bf16 tiled, r in [0,3)
//   48MB + r*1MB      Xb[r] bf16 tiled (pre *log2e), r in [0,3)
#define WT_BASE   (16u << 20)
#define WT_STRIDE  4194304u   /* u16 elems = 8MB */
#define XB_BASE   (48u << 20)
#define XB_STRIDE  524288u    /* u16 elems = 1MB */

__device__ __forceinline__ u16 f2bf(float f) {
    unsigned u = __builtin_bit_cast(unsigned, f);
    u += 0x7fff + ((u >> 16) & 1);              // RNE
    return (u16)(u >> 16);
}

__device__ __forceinline__ float exp2_fast(float x) {
#if __has_builtin(__builtin_amdgcn_exp2f)
    return __builtin_amdgcn_exp2f(x);
#else
    float r; asm("v_exp_f32 %0, %1" : "=v"(r) : "v"(x)); return r;
#endif
}

__device__ __forceinline__ float hsum_neg(h16x2 s) {
#if __has_builtin(__builtin_amdgcn_fdot2)
    const h16x2 n1 = {(_Float16)-1.0f, (_Float16)-1.0f};
    return __builtin_amdgcn_fdot2(s, n1, 0.0f, false);
#else
    return -((float)s[0] + (float)s[1]);
#endif
}

// ---------------------------------------------------------------------------
// Prep: blocks 0..127 = T transpose+convert; 128..383 = X convert + copy.
// Writes 3 identical operand regions (diagnostic L2-cycling support).
// ---------------------------------------------------------------------------
__global__ __launch_bounds__(256)
void k_prep(const float* __restrict__ X, const float* __restrict__ T,
            u16* __restrict__ Wt, u16* __restrict__ Xb,
            float* __restrict__ out) {
    const int b = blockIdx.x, t = threadIdx.x;
    if (b < 128) {
        const int np = (b & 3) * 256 + t;
        const int n  = np * 2;
        const int kg = b >> 2;
        const int nt = n >> 4, n16 = n & 15;
#pragma unroll
        for (int kc = 0; kc < 8; ++kc) {
            const int kb = kg * 64 + kc * 8;
            u16 h0[8], h1[8];
#pragma unroll
            for (int r = 0; r < 8; ++r) {
                float2 v = *(const float2*)(T + (size_t)(kb + r) * NCOL + n);
                h0[r] = f2bf(v.x);
                h1[r] = f2bf(v.y);
            }
            const size_t off = ((size_t)(nt * 256 + kg * 8 + kc) * 16 + n16) * 8;
#pragma unroll
            for (int rg = 0; rg < 3; ++rg) {
                u16* dst = Wt + (size_t)rg * WT_STRIDE + off;
                *(float4*)dst       = *(float4*)h0;
                *(float4*)(dst + 8) = *(float4*)h1;
            }
        }
    } else {
        const int g   = b - 128;
        const int rt  = g >> 4;
        const int kc  = (g & 15) * 16 + (t & 15);
        const int r16 = t >> 4;
        const int row = rt * 16 + r16;
        const float* src = X + (size_t)row * IN_F + kc * 8;
        float4 v0 = *(const float4*)src;
        float4 v1 = *(const float4*)(src + 4);
        u16 h[8] = {f2bf(v0.x * LOG2E), f2bf(v0.y * LOG2E),
                    f2bf(v0.z * LOG2E), f2bf(v0.w * LOG2E),
                    f2bf(v1.x * LOG2E), f2bf(v1.y * LOG2E),
                    f2bf(v1.z * LOG2E), f2bf(v1.w * LOG2E)};
        const size_t off = ((size_t)(rt * 256 + kc) * 16 + r16) * 8;
#pragma unroll
        for (int rg = 0; rg < 3; ++rg)
            *(float4*)(Xb + (size_t)rg * XB_STRIDE + off) = *(float4*)h;
        float* od = out + (size_t)row * OSTRIDE + kc * 8;
        *(float4*)od       = v0;
        *(float4*)(od + 4) = v1;
    }
}

// ---------------------------------------------------------------------------
// MFMA GEMM v3 (8-way in-block split-K), rep-looped for diagnosis.
// Region cycling %3 (27MB working set > aggregate L2) reproduces the real
// L3-resident / L2-cold first-read state every rep.
// ---------------------------------------------------------------------------
__global__ __launch_bounds__(512, 4)
void k_gemm(const u16* __restrict__ XbB, const u16* __restrict__ WtB,
            u16* __restrict__ Mh, int reps, size_t zoff) {
    __shared__ float L[8][32][33];     // 33.8 KB
    const int t = threadIdx.x, l = t & 63, kcw = t >> 6;
    const int bid = blockIdx.x;
    const int R = bid >> 6;            // 0..7
    const int C = bid & 63;            // 0..63 (bid%8=C%8: XCD grouping)
    const int lo = (l >> 4) * 128 + (l & 15) * 8;
    const int lq = l >> 4, lm = l & 15;

    for (int rep = 0; rep < reps; ++rep) {
        const int rg = rep % 3;
        const u16* Xb = XbB + (size_t)rg * XB_STRIDE + (size_t)rep * zoff;
        const u16* Wt = WtB + (size_t)rg * WT_STRIDE + (size_t)rep * zoff;

        const u16* ap0 = Xb + (size_t)(R * 2) * 32768 + kcw * 4096 + lo;
        const u16* ap1 = ap0 + 32768;
        const u16* bp0 = Wt + (size_t)(C * 2) * 32768 + kcw * 4096 + lo;
        const u16* bp1 = bp0 + 32768;

        f32x4 c00 = {0.f,0.f,0.f,0.f}, c01 = {0.f,0.f,0.f,0.f};
        f32x4 c10 = {0.f,0.f,0.f,0.f}, c11 = {0.f,0.f,0.f,0.f};

#pragma unroll 8
        for (int s = 0; s < 8; ++s) {
            bf16x8 a0 = *(const bf16x8*)(ap0 + s * 512);
            bf16x8 a1 = *(const bf16x8*)(ap1 + s * 512);
            bf16x8 b0 = *(const bf16x8*)(bp0 + s * 512);
            bf16x8 b1 = *(const bf16x8*)(bp1 + s * 512);
            c00 = __builtin_amdgcn_mfma_f32_16x16x32_bf16(a0, b0, c00, 0, 0, 0);
            c01 = __builtin_amdgcn_mfma_f32_16x16x32_bf16(a0, b1, c01, 0, 0, 0);
            c10 = __builtin_amdgcn_mfma_f32_16x16x32_bf16(a1, b0, c10, 0, 0, 0);
            c11 = __builtin_amdgcn_mfma_f32_16x16x32_bf16(a1, b1, c11, 0, 0, 0);
        }

#define PUT(acc, qi, qj) do { \
        _Pragma("unroll") \
        for (int r = 0; r < 4; ++r) \
            L[kcw][(qj) * 16 + lm][(qi) * 16 + lq * 4 + r] = acc[r]; \
    } while (0)
        PUT(c00, 0, 0); PUT(c01, 0, 1); PUT(c10, 1, 0); PUT(c11, 1, 1);
#undef PUT
        __syncthreads();

        if (t < 256) {
            const int o2 = t >> 6;             // 0..3
            const int jl = (t & 63) >> 1;      // 0..31
            const int k0 = (t & 1) * 4;        // 0 or 4
            float v[4];
#pragma unroll
            for (int i = 0; i < 4; ++i) {
                const int c = o2 * 8 + k0 + i;
                float s0 = (L[0][c][jl] + L[1][c][jl]) + (L[2][c][jl] + L[3][c][jl]);
                float s1 = (L[4][c][jl] + L[5][c][jl]) + (L[6][c][jl] + L[7][c][jl]);
                v[i] = s0 + s1;
            }
            fp16x2 p0 = __builtin_amdgcn_cvt_pkrtz(v[0], v[1]);
            fp16x2 p1 = __builtin_amdgcn_cvt_pkrtz(v[2], v[3]);
            uint2 pk = {__builtin_bit_cast(u32, p0), __builtin_bit_cast(u32, p1)};
            *(uint2*)(Mh + ((size_t)(C * 4 + o2) * 256 + R * 32 + jl) * 8 + k0) = pk;
        }
        __syncthreads();   // protect L across reps
    }
}

// ---------------------------------------------------------------------------
// Pairwise L1-exp2 (1024 threads), rep-looped for diagnosis (idempotent).
// ---------------------------------------------------------------------------
__global__ __launch_bounds__(1024)
void k_pair(const u16* __restrict__ MhB, float* __restrict__ out,
            int reps, size_t zoff) {
    __shared__ __align__(16) uint4 Msh[BATCH];    // 4 KB
    __shared__ float Ps[1024];
    const int o = blockIdx.x, t = threadIdx.x;
    const int j = t & 255, q = t >> 8;

    for (int rep = 0; rep < reps; ++rep) {
        const u16* Mh = MhB + (size_t)rep * zoff;
        if (t < 256) Msh[t] = ((const uint4*)(Mh + (size_t)o * 2048))[t];
        __syncthreads();

        uint4 mm = Msh[j];
        const h16x2 m0 = __builtin_bit_cast(h16x2, mm.x);
        const h16x2 m1 = __builtin_bit_cast(h16x2, mm.y);
        const h16x2 m2 = __builtin_bit_cast(h16x2, mm.z);
        const h16x2 m3 = __builtin_bit_cast(h16x2, mm.w);

        float acc = 0.f;
        const int i0 = q * 64;
#pragma unroll 8
        for (int i = i0; i < i0 + 64; ++i) {
            uint4 uu = Msh[i];                    // broadcast ds_read_b128
            h16x2 d0 = __builtin_bit_cast(h16x2, uu.x) - m0;
            h16x2 d1 = __builtin_bit_cast(h16x2, uu.y) - m1;
            h16x2 d2 = __builtin_bit_cast(h16x2, uu.z) - m2;
            h16x2 d3 = __builtin_bit_cast(h16x2, uu.w) - m3;
            h16x2 e0 = __builtin_bit_cast(h16x2, __builtin_bit_cast(u32, d0) & 0x7fff7fffu);
            h16x2 e1 = __builtin_bit_cast(h16x2, __builtin_bit_cast(u32, d1) & 0x7fff7fffu);
            h16x2 e2 = __builtin_bit_cast(h16x2, __builtin_bit_cast(u32, d2) & 0x7fff7fffu);
            h16x2 e3 = __builtin_bit_cast(h16x2, __builtin_bit_cast(u32, d3) & 0x7fff7fffu);
            h16x2 s = (e0 + e1) + (e2 + e3);
            acc += exp2_fast(hsum_neg(s));
        }
        Ps[t] = acc;
        __syncthreads();
        if (t < 256)
            out[(size_t)t * OSTRIDE + IN_F + o] =
                ((Ps[t] + Ps[t + 256]) + (Ps[t + 512] + Ps[t + 768])) - 1.0f;
        __syncthreads();   // protect Msh/Ps across reps
    }
}

extern "C" void kernel_launch(void* const* d_in, const int* in_sizes, int n_in,
                              void* d_out, int out_size, void* d_ws, size_t ws_size,
                              hipStream_t stream) {
    const float* x = (const float*)d_in[0];   // [256, 2048]
    const float* T = (const float*)d_in[1];   // [2048][2048] flattened
    float* out = (float*)d_out;               // [256, 2304]
    char* ws = (char*)d_ws;
    u16* Mh = (u16*)ws;
    u16* Wt = (u16*)(ws + WT_BASE);
    u16* Xb = (u16*)(ws + XB_BASE);
    const size_t zoff = (size_t)(in_sizes[0] - 524288);   // == 0, opaque

    k_prep<<<384, 256, 0, stream>>>(x, T, Wt, Xb, out);
    k_gemm<<<512, 512, 0, stream>>>(Xb, Wt, Mh, 16, zoff);
    k_pair<<<256, 1024, 0, stream>>>(Mh, out, 16, zoff);
}

// Round 12
// 29.749 us; speedup vs baseline: 11.7001x; 7.8983x over previous
//
#include <hip/hip_runtime.h>
#include <math.h>

#define BATCH   256
#define IN_F    2048
#define OUT_F   256
#define NCOL    2048    /* OUT_F*KD */
#define OSTRIDE 2304    /* IN_F + OUT_F */
#define LOG2E   1.4426950408889634f

typedef float    f32x4  __attribute__((ext_vector_type(4)));
typedef short    bf16x8 __attribute__((ext_vector_type(8)));
typedef _Float16 h16x2  __attribute__((ext_vector_type(2)));
typedef __fp16   fp16x2 __attribute__((ext_vector_type(2)));
typedef unsigned short u16;
typedef unsigned int   u32;

// ws layout:
//   [0, 1MB)   Mh f16 [256 o][256 j][8 k]
//   [16,24MB)  Wt bf16 tiled [nt(128)][kc(256)][n16(16)][8]
//   [64,65MB)  Xb bf16 tiled [rt(16)][kc(256)][r16(16)][8] (pre *log2e)
#define WT_BASE   (16u << 20)
#define XB_BASE   (64u << 20)

__device__ __forceinline__ u16 f2bf(float f) {
    unsigned u = __builtin_bit_cast(unsigned, f);
    u += 0x7fff + ((u >> 16) & 1);              // RNE
    return (u16)(u >> 16);
}

__device__ __forceinline__ float exp2_fast(float x) {
#if __has_builtin(__builtin_amdgcn_exp2f)
    return __builtin_amdgcn_exp2f(x);
#else
    float r; asm("v_exp_f32 %0, %1" : "=v"(r) : "v"(x)); return r;
#endif
}

__device__ __forceinline__ float hsum_neg(h16x2 s) {
#if __has_builtin(__builtin_amdgcn_fdot2)
    const h16x2 n1 = {(_Float16)-1.0f, (_Float16)-1.0f};
    return __builtin_amdgcn_fdot2(s, n1, 0.0f, false);
#else
    return -((float)s[0] + (float)s[1]);
#endif
}

// ---------------------------------------------------------------------------
// Prep: blocks 0..127 = T transpose+convert; 128..383 = X convert + copy.
// ---------------------------------------------------------------------------
__global__ __launch_bounds__(256)
void k_prep(const float* __restrict__ X, const float* __restrict__ T,
            u16* __restrict__ Wt, u16* __restrict__ Xb,
            float* __restrict__ out) {
    const int b = blockIdx.x, t = threadIdx.x;
    if (b < 128) {
        const int np = (b & 3) * 256 + t;
        const int n  = np * 2;
        const int kg = b >> 2;
        const int nt = n >> 4, n16 = n & 15;
#pragma unroll
        for (int kc = 0; kc < 8; ++kc) {
            const int kb = kg * 64 + kc * 8;
            u16 h0[8], h1[8];
#pragma unroll
            for (int r = 0; r < 8; ++r) {
                float2 v = *(const float2*)(T + (size_t)(kb + r) * NCOL + n);
                h0[r] = f2bf(v.x);
                h1[r] = f2bf(v.y);
            }
            u16* dst = Wt + ((size_t)(nt * 256 + kg * 8 + kc) * 16 + n16) * 8;
            *(float4*)dst       = *(float4*)h0;
            *(float4*)(dst + 8) = *(float4*)h1;
        }
    } else {
        const int g   = b - 128;
        const int rt  = g >> 4;
        const int kc  = (g & 15) * 16 + (t & 15);
        const int r16 = t >> 4;
        const int row = rt * 16 + r16;
        const float* src = X + (size_t)row * IN_F + kc * 8;
        float4 v0 = *(const float4*)src;
        float4 v1 = *(const float4*)(src + 4);
        u16 h[8] = {f2bf(v0.x * LOG2E), f2bf(v0.y * LOG2E),
                    f2bf(v0.z * LOG2E), f2bf(v0.w * LOG2E),
                    f2bf(v1.x * LOG2E), f2bf(v1.y * LOG2E),
                    f2bf(v1.z * LOG2E), f2bf(v1.w * LOG2E)};
        *(float4*)(Xb + ((size_t)(rt * 256 + kc) * 16 + r16) * 8) = *(float4*)h;
        float* od = out + (size_t)row * OSTRIDE + kc * 8;
        *(float4*)od       = v0;
        *(float4*)(od + 4) = v1;
    }
}

// ---------------------------------------------------------------------------
// MFMA GEMM (8-way in-block split-K). 512 blocks x 8 waves, 2 blocks/CU.
// bid = R*64 + C -> bid%8 = C%8 keeps same-B-panel blocks on one XCD.
// C/D frag: col = l&15, row = (l>>4)*4 + reg  [m89/m91].
// ---------------------------------------------------------------------------
__global__ __launch_bounds__(512, 4)
void k_gemm(const u16* __restrict__ Xb, const u16* __restrict__ Wt,
            u16* __restrict__ Mh) {
    __shared__ float L[8][32][33];     // 33.8 KB
    const int t = threadIdx.x, l = t & 63, kcw = t >> 6;
    const int bid = blockIdx.x;
    const int R = bid >> 6;            // 0..7
    const int C = bid & 63;            // 0..63

    const int lo = (l >> 4) * 128 + (l & 15) * 8;
    const u16* ap0 = Xb + (size_t)(R * 2) * 32768 + kcw * 4096 + lo;
    const u16* ap1 = ap0 + 32768;
    const u16* bp0 = Wt + (size_t)(C * 2) * 32768 + kcw * 4096 + lo;
    const u16* bp1 = bp0 + 32768;

    f32x4 c00 = {0.f,0.f,0.f,0.f}, c01 = {0.f,0.f,0.f,0.f};
    f32x4 c10 = {0.f,0.f,0.f,0.f}, c11 = {0.f,0.f,0.f,0.f};

#pragma unroll 8
    for (int s = 0; s < 8; ++s) {
        bf16x8 a0 = *(const bf16x8*)(ap0 + s * 512);
        bf16x8 a1 = *(const bf16x8*)(ap1 + s * 512);
        bf16x8 b0 = *(const bf16x8*)(bp0 + s * 512);
        bf16x8 b1 = *(const bf16x8*)(bp1 + s * 512);
        c00 = __builtin_amdgcn_mfma_f32_16x16x32_bf16(a0, b0, c00, 0, 0, 0);
        c01 = __builtin_amdgcn_mfma_f32_16x16x32_bf16(a0, b1, c01, 0, 0, 0);
        c10 = __builtin_amdgcn_mfma_f32_16x16x32_bf16(a1, b0, c10, 0, 0, 0);
        c11 = __builtin_amdgcn_mfma_f32_16x16x32_bf16(a1, b1, c11, 0, 0, 0);
    }

    const int lq = l >> 4, lm = l & 15;
#define PUT(acc, qi, qj) do { \
        _Pragma("unroll") \
        for (int r = 0; r < 4; ++r) \
            L[kcw][(qj) * 16 + lm][(qi) * 16 + lq * 4 + r] = acc[r]; \
    } while (0)
    PUT(c00, 0, 0); PUT(c01, 0, 1); PUT(c10, 1, 0); PUT(c11, 1, 1);
#undef PUT
    __syncthreads();

    if (t < 256) {
        const int o2 = t >> 6;             // 0..3
        const int jl = (t & 63) >> 1;      // 0..31
        const int k0 = (t & 1) * 4;        // 0 or 4
        float v[4];
#pragma unroll
        for (int i = 0; i < 4; ++i) {
            const int c = o2 * 8 + k0 + i;
            float s0 = (L[0][c][jl] + L[1][c][jl]) + (L[2][c][jl] + L[3][c][jl]);
            float s1 = (L[4][c][jl] + L[5][c][jl]) + (L[6][c][jl] + L[7][c][jl]);
            v[i] = s0 + s1;
        }
        fp16x2 p0 = __builtin_amdgcn_cvt_pkrtz(v[0], v[1]);
        fp16x2 p1 = __builtin_amdgcn_cvt_pkrtz(v[2], v[3]);
        uint2 pk = {__builtin_bit_cast(u32, p0), __builtin_bit_cast(u32, p1)};
        *(uint2*)(Mh + ((size_t)(C * 4 + o2) * 256 + R * 32 + jl) * 8 + k0) = pk;
    }
}

// ---------------------------------------------------------------------------
// Pairwise L1-exp2 v3: j-blocked x4. Block = o, 1024 threads.
// Lane: jg = t&63 owns j in {jg, jg+64, jg+128, jg+192} (m-rows in regs);
// q = t>>6 (wave-uniform) owns i-chunk [q*16, q*16+16). One broadcast
// ds_read_b128 per i feeds 4 pairs -> LDS bytes/pair 16B -> 4B.
// Reduce via Ps[16][256] (2 lanes/bank = conflict-free).
// ---------------------------------------------------------------------------
__global__ __launch_bounds__(1024)
void k_pair(const u16* __restrict__ Mh, float* __restrict__ out) {
    __shared__ __align__(16) uint4 Msh[BATCH];    // 4 KB
    __shared__ float Ps[16][256];                 // 16 KB
    const int o = blockIdx.x, t = threadIdx.x;

    if (t < 256) Msh[t] = ((const uint4*)(Mh + (size_t)o * 2048))[t];
    __syncthreads();

    const int jg = t & 63, q = t >> 6;
    h16x2 m[4][4];
#pragma unroll
    for (int c = 0; c < 4; ++c) {
        uint4 mm = Msh[jg + 64 * c];
        m[c][0] = __builtin_bit_cast(h16x2, mm.x);
        m[c][1] = __builtin_bit_cast(h16x2, mm.y);
        m[c][2] = __builtin_bit_cast(h16x2, mm.z);
        m[c][3] = __builtin_bit_cast(h16x2, mm.w);
    }

    float acc[4] = {0.f, 0.f, 0.f, 0.f};
    const int i0 = q * 16;
#pragma unroll 2
    for (int ii = 0; ii < 16; ++ii) {
        uint4 uu = Msh[i0 + ii];                  // broadcast ds_read_b128
        const h16x2 u0 = __builtin_bit_cast(h16x2, uu.x);
        const h16x2 u1 = __builtin_bit_cast(h16x2, uu.y);
        const h16x2 u2 = __builtin_bit_cast(h16x2, uu.z);
        const h16x2 u3 = __builtin_bit_cast(h16x2, uu.w);
#pragma unroll
        for (int c = 0; c < 4; ++c) {
            h16x2 d0 = u0 - m[c][0];
            h16x2 d1 = u1 - m[c][1];
            h16x2 d2 = u2 - m[c][2];
            h16x2 d3 = u3 - m[c][3];
            h16x2 e0 = __builtin_bit_cast(h16x2, __builtin_bit_cast(u32, d0) & 0x7fff7fffu);
            h16x2 e1 = __builtin_bit_cast(h16x2, __builtin_bit_cast(u32, d1) & 0x7fff7fffu);
            h16x2 e2 = __builtin_bit_cast(h16x2, __builtin_bit_cast(u32, d2) & 0x7fff7fffu);
            h16x2 e3 = __builtin_bit_cast(h16x2, __builtin_bit_cast(u32, d3) & 0x7fff7fffu);
            h16x2 s = (e0 + e1) + (e2 + e3);
            acc[c] += exp2_fast(hsum_neg(s));
        }
    }
#pragma unroll
    for (int c = 0; c < 4; ++c) Ps[q][jg + 64 * c] = acc[c];
    __syncthreads();

    if (t < 256) {
        float s = 0.f;
#pragma unroll
        for (int q2 = 0; q2 < 16; ++q2) s += Ps[q2][t];
        out[(size_t)t * OSTRIDE + IN_F + o] = s - 1.0f;
    }
}

extern "C" void kernel_launch(void* const* d_in, const int* in_sizes, int n_in,
                              void* d_out, int out_size, void* d_ws, size_t ws_size,
                              hipStream_t stream) {
    const float* x = (const float*)d_in[0];   // [256, 2048]
    const float* T = (const float*)d_in[1];   // [2048][2048] flattened
    float* out = (float*)d_out;               // [256, 2304]
    char* ws = (char*)d_ws;
    u16* Mh = (u16*)ws;
    u16* Wt = (u16*)(ws + WT_BASE);
    u16* Xb = (u16*)(ws + XB_BASE);

    k_prep<<<384, 256, 0, stream>>>(x, T, Wt, Xb, out);
    k_gemm<<<512, 512, 0, stream>>>(Xb, Wt, Mh);
    k_pair<<<256, 1024, 0, stream>>>(Mh, out);
}